// Round 14
// baseline (4526.221 us; speedup 1.0000x reference)
//
#include <hip/hip_runtime.h>
#include <math.h>

#define NN 3072
#define EPSG 1e-20f
#define EDGE_CAP 53248          // ~47.2K expected edges + margin
#define RCH 128                 // rows per chunk
#define NCH 24                  // chunks (24*128 = 3072)
typedef unsigned long long u64;

// ---------- prep 1: rowsum0[i] = sum_c adj[i][c] ----------
__global__ __launch_bounds__(256) void rowsum_kernel(const float* __restrict__ adj,
                                                     float* __restrict__ rowsum) {
    int row = blockIdx.x;
    const float* r = adj + (size_t)row * NN;
    float s = 0.f;
    for (int c = threadIdx.x; c < NN; c += 256) s += r[c];
#pragma unroll
    for (int off = 32; off > 0; off >>= 1) s += __shfl_down(s, off);
    __shared__ float ps[4];
    if ((threadIdx.x & 63) == 0) ps[threadIdx.x >> 6] = s;
    __syncthreads();
    if (threadIdx.x == 0) rowsum[row] = (ps[0] + ps[1]) + (ps[2] + ps[3]);
}

// ---------- prep 2a: per-chunk column counts ----------
__global__ __launch_bounds__(256) void cnt_kernel(const float* __restrict__ adj,
                                                  unsigned* __restrict__ cnt) {
    int c = blockIdx.x * 256 + threadIdx.x;
    const float* col = adj + (size_t)(blockIdx.y * RCH) * NN + c;
    unsigned n = 0;
#pragma unroll 4
    for (int i = 0; i < RCH; ++i)
        n += (col[(size_t)i * NN] != 0.0f) ? 1u : 0u;
    cnt[blockIdx.y * NN + c] = n;
}

// ---------- prep 2b: total per-column counts ----------
__global__ __launch_bounds__(256) void colsum_kernel(const unsigned* __restrict__ cnt,
                                                     unsigned* __restrict__ colcnt) {
    int c = blockIdx.x * 256 + threadIdx.x;
    unsigned n = 0;
    for (int by = 0; by < NCH; ++by) n += cnt[by * NN + c];
    colcnt[c] = n;
}

// ---------- prep 2c: exclusive scan of column counts (1 wave) ----------
__global__ __launch_bounds__(64) void scan_kernel(const unsigned* __restrict__ colcnt,
                                                  unsigned* __restrict__ eoff) {
    int lane = threadIdx.x;
    unsigned tot = 0;
    for (int k = 0; k < 48; ++k) tot += colcnt[lane * 48 + k];
    unsigned x = tot;
    for (int off = 1; off < 64; off <<= 1) {
        unsigned y = __shfl_up(x, off);
        if (lane >= off) x += y;
    }
    unsigned run = x - tot;
    for (int k = 0; k < 48; ++k) {
        unsigned c = colcnt[lane * 48 + k];
        eoff[lane * 48 + k] = run;
        run += c;
    }
    if (lane == 63) eoff[NN] = run;
}

// ---------- prep 2d: per-(chunk,column) start offsets ----------
__global__ __launch_bounds__(256) void choff_kernel(const unsigned* __restrict__ cnt,
                                                    const unsigned* __restrict__ eoff,
                                                    unsigned* __restrict__ choff) {
    int c = blockIdx.x * 256 + threadIdx.x;
    unsigned run = eoff[c];
    for (int by = 0; by < NCH; ++by) {
        choff[by * NN + c] = run;
        run += cnt[by * NN + c];
    }
}

// ---------- prep 2e: fill CSC edge lists ----------
__global__ __launch_bounds__(256) void fill2_kernel(const float* __restrict__ adj,
                                                    const unsigned* __restrict__ choff,
                                                    unsigned short* __restrict__ edges) {
    int c = blockIdx.x * 256 + threadIdx.x;
    int r0 = blockIdx.y * RCH;
    unsigned off = choff[blockIdx.y * NN + c];
    const float* col = adj + (size_t)r0 * NN + c;
    for (int i = 0; i < RCH; ++i) {
        if (col[(size_t)i * NN] != 0.0f) {
            if (off < EDGE_CAP) edges[off] = (unsigned short)(r0 + i);
            ++off;
        }
    }
}

// monotonic order-preserving float->u32 map (never 0 for finite inputs)
__device__ __forceinline__ unsigned enc32(float v) {
    unsigned u = __float_as_uint(v);
    return (u & 0x80000000u) ? ~u : (u | 0x80000000u);
}

// ---------- prep 3: gumbel + derived per-node arrays ----------
__global__ __launch_bounds__(256) void gumbel_kernel(const float* __restrict__ logits,
                                                     const float* __restrict__ unif,
                                                     const float* __restrict__ rowsum,
                                                     float* __restrict__ out,
                                                     float* __restrict__ elog,
                                                     unsigned* __restrict__ keyenc,
                                                     int* __restrict__ indeg) {
    int j = blockIdx.x * 256 + threadIdx.x;
    float lg = logits[j];
    float u  = unif[j];
    float g  = lg + (-logf(-logf(u + EPSG) + EPSG));
    out[NN + j] = g;                 // gumbel_logits output
    elog[j] = expf(lg);
    keyenc[j] = enc32(g);
    indeg[j] = (int)rowsum[j];
}

// DPP wave64 max-reduce: result valid in lane 63
__device__ __forceinline__ unsigned wmax_u32(unsigned v) {
    unsigned t;
    t = (unsigned)__builtin_amdgcn_update_dpp(0, (int)v, 0x111, 0xf, 0xf, true); v = t > v ? t : v;
    t = (unsigned)__builtin_amdgcn_update_dpp(0, (int)v, 0x112, 0xf, 0xf, true); v = t > v ? t : v;
    t = (unsigned)__builtin_amdgcn_update_dpp(0, (int)v, 0x114, 0xf, 0xf, true); v = t > v ? t : v;
    t = (unsigned)__builtin_amdgcn_update_dpp(0, (int)v, 0x118, 0xf, 0xf, true); v = t > v ? t : v;
    t = (unsigned)__builtin_amdgcn_update_dpp(0, (int)v, 0x142, 0xf, 0xf, true); v = t > v ? t : v;
    t = (unsigned)__builtin_amdgcn_update_dpp(0, (int)v, 0x143, 0xf, 0xf, true); v = t > v ? t : v;
    return v;
}
__device__ __forceinline__ float wsum_f32(float v) {
    int t;
    t = __builtin_amdgcn_update_dpp(0, __float_as_int(v), 0x111, 0xf, 0xf, true); v += __int_as_float(t);
    t = __builtin_amdgcn_update_dpp(0, __float_as_int(v), 0x112, 0xf, 0xf, true); v += __int_as_float(t);
    t = __builtin_amdgcn_update_dpp(0, __float_as_int(v), 0x114, 0xf, 0xf, true); v += __int_as_float(t);
    t = __builtin_amdgcn_update_dpp(0, __float_as_int(v), 0x118, 0xf, 0xf, true); v += __int_as_float(t);
    t = __builtin_amdgcn_update_dpp(0, __float_as_int(v), 0x142, 0xf, 0xf, true); v += __int_as_float(t);
    t = __builtin_amdgcn_update_dpp(0, __float_as_int(v), 0x143, 0xf, 0xf, true); v += __int_as_float(t);
    return v;
}
__device__ __forceinline__ int rdlane(int v, int l) { return __builtin_amdgcn_readlane(v, l); }
__device__ __forceinline__ u64 rdlane64(u64 v, int l) {
    unsigned lo = (unsigned)rdlane((int)(unsigned)v, l);
    unsigned hi = (unsigned)rdlane((int)(unsigned)(v >> 32), l);
    return ((u64)hi << 32) | lo;
}

// sorted insert into descending top-4 (g0..g3 monotone since list sorted)
__device__ __forceinline__ void ins4(u64 kk, u64& k0, u64& k1, u64& k2, u64& k3,
                                     int& valid, bool& ovf) {
    bool g0 = kk > k0, g1 = kk > k1, g2 = kk > k2, g3 = kk > k3;
    u64 n0 = g0 ? kk : k0;
    u64 n1 = g0 ? k0 : (g1 ? kk : k1);
    u64 n2 = g1 ? k1 : (g2 ? kk : k2);
    u64 n3 = g2 ? k2 : (g3 ? kk : k3);
    u64 pushed = g3 ? k3 : kk;
    k0 = n0; k1 = n1; k2 = n2; k3 = n3;
    ovf |= (pushed != 0ULL);
    valid = g3 ? (valid < 4 ? valid + 1 : 4) : valid;
}

// rebuild exact top-4 from eligibility mask (popcount is small: ~1-3 bits)
__device__ __forceinline__ void refill4(const u64* s_key, int lane, u64 elig,
                                        u64& k0, u64& k1, u64& k2, u64& k3,
                                        int& valid, bool& ovf) {
    k0 = k1 = k2 = k3 = 0ULL;
    int cnt = 0; bool dum = false; int v2 = 0;
    u64 m = elig;
    while (m) {
        int i = (int)__ffsll(m) - 1; m &= m - 1;
        int j = (i << 6) | lane;
        u64 nw = s_key[j];
        u64 kk = ((nw & 0xFFFFFFFFULL) << 32) | (unsigned)(~j);
        ins4(kk, k0, k1, k2, k3, v2, dum);
        ++cnt;
    }
    valid = cnt > 4 ? 4 : cnt;
    ovf = cnt > 4;
}

// ---------- sequential topo-sort: batched selection (B=8) ----------
__global__ __launch_bounds__(256) void topo_kernel(const float* __restrict__ elog_g,
                                                   const unsigned* __restrict__ keyenc_g,
                                                   const int* __restrict__ indeg_g,
                                                   const unsigned* __restrict__ eoff_g,
                                                   const unsigned short* __restrict__ edges_g,
                                                   float* __restrict__ gslog,
                                                   unsigned* __restrict__ gssel,
                                                   float* __restrict__ out) {
    __shared__ u64            s_key[NN];                // hi=indeg, lo=keyenc (static)
    __shared__ float          s_elog[NN];
    __shared__ unsigned       s_meta[NN];               // eoff | d<<20
    __shared__ unsigned short s_edges[EDGE_CAP + 128];

    const int tid = threadIdx.x;

    // ---- cooperative staging (all 4 waves) ----
    for (int j = tid; j < NN; j += 256) {
        unsigned e0 = eoff_g[j];
        unsigned e1 = eoff_g[j + 1];
        s_key[j] = ((u64)(unsigned)indeg_g[j] << 32) | keyenc_g[j];
        s_elog[j] = elog_g[j];
        s_meta[j] = e0 | ((e1 - e0) << 20);
    }
    {
        unsigned total = eoff_g[NN];
        unsigned n32 = (total + 1) >> 1;
        unsigned cap32 = (EDGE_CAP + 128) / 2;
        if (n32 > cap32) n32 = cap32;
        for (unsigned x = tid; x < n32; x += 256)
            ((unsigned*)s_edges)[x] = ((const unsigned*)edges_g)[x];
    }
    __syncthreads();
    if (tid >= 64) return;              // wave 0 continues alone
    const int lane = tid;

    // ---- init: eligibility mask, S, exact top-4 per lane ----
    u64 elig = 0ULL;
    float S;
    {
        float ssl = 0.f;
        for (int i = 0; i < 48; ++i) {
            int j = (i << 6) | lane;
            u64 nw = s_key[j];
            if ((unsigned)(nw >> 32) == 0u) {
                elig |= 1ULL << i;
                ssl += s_elog[j];
            }
        }
        float tot = wsum_f32(ssl);
        S = __int_as_float(rdlane(__float_as_int(tot), 63));
    }
    u64 k0, k1, k2, k3;
    int valid; bool ovf;
    refill4(s_key, lane, elig, k0, k1, k2, k3, valid, ovf);

    int t = 0;
    int guard = 0;
    while (t < NN) {
        if (++guard > NN + 64) break;   // safety: never hang

        // ---- refill needy lanes ----
        bool need = ovf && (valid <= 2);
        if (__ballot(need)) {
            if (need) refill4(s_key, lane, elig, k0, k1, k2, k3, valid, ovf);
        }

        // ---- BUILD: extract exact global top-8 (k-way merge) ----
        u64 c[8];
        int L = 0, p = 0;
        bool stop = false;
#pragma unroll
        for (int b = 0; b < 8; ++b) {
            c[b] = 0ULL;
            if (!stop) {
                u64 w = (p == 0) ? k0 : (p == 1) ? k1 : (p == 2) ? k2 : (p == 3) ? k3 : 0ULL;
                if (p >= valid) w = 0ULL;
                unsigned whi = (unsigned)(w >> 32);
                unsigned mx = (unsigned)rdlane((int)wmax_u32(whi), 63);
                if (mx == 0u) {
                    stop = true;
                } else {
                    u64 ball = __ballot(whi == mx);
                    int gl = (int)__ffsll(ball) - 1;
                    c[b] = rdlane64(w, gl);
                    L = b + 1;
                    bool me = (lane == gl);
                    if (me) ++p;
                    if (__ballot(me && p >= valid && ovf)) stop = true;  // hidden keys
                }
            }
        }
        if (L == 0) {
            if (__ballot(ovf) == 0ULL) break;   // nothing left anywhere
            if (ovf) refill4(s_key, lane, elig, k0, k1, k2, k3, valid, ovf);
            continue;
        }

        // ---- prefetch metas / edges / elog for all items ----
        unsigned e0a[8]; int da[8]; int ewa[8]; float elca[8];
#pragma unroll
        for (int b = 0; b < 8; ++b) { e0a[b] = 0u; da[b] = 0; ewa[b] = 0; elca[b] = 0.f; }
#pragma unroll
        for (int b = 0; b < 8; ++b) {
            if (b < L) {
                unsigned sel = ~(unsigned)c[b];
                unsigned m = s_meta[sel];
                e0a[b] = m & 0xFFFFFu;
                da[b] = (int)(m >> 20);
            }
        }
#pragma unroll
        for (int b = 1; b < 8; ++b) { if (b < L && da[b] > 64) L = b; }  // monster cols solo
#pragma unroll
        for (int b = 0; b < 8; ++b) {
            if (b < L) {
                unsigned sel = ~(unsigned)c[b];
                ewa[b] = (int)s_edges[e0a[b] + (lane < da[b] ? lane : 0)];
                elca[b] = s_elog[sel];
            }
        }

        // ---- pipelined atomic decrements (returns old {indeg,keyenc}) ----
        u64 olda[8];
#pragma unroll
        for (int b = 0; b < 8; ++b) {
            olda[b] = 0ULL;
            if (b < L && lane < da[b])
                olda[b] = atomicAdd(&s_key[ewa[b]], 0xFFFFFFFF00000000ULL);
        }

        // ---- apply items serially (cheap); abort on ordering hazard ----
        u64 pmax = 0ULL;
        u64 pi0 = 0ULL, pi1 = 0ULL;
        bool pend_ovf = false;
        int selcnt = 0;
        int done = L;
#pragma unroll
        for (int b = 0; b < 8; ++b) {
            if (b < done) {
                unsigned sel = ~(unsigned)c[b];
                if (lane == 0) { gslog[t + b] = S; gssel[t + b] = sel; }
                if (lane == (int)(sel & 63u)) {
                    ++selcnt;
                    elig &= ~(1ULL << (sel >> 6));
                }
                S -= elca[b];

                bool trip = false;
                u64 pend = (lane < da[b] && (unsigned)(olda[b] >> 32) == 1u)
                         ? (((olda[b] & 0xFFFFFFFFULL) << 32) | (unsigned)(~(unsigned)ewa[b]))
                         : 0ULL;
                u64 ib = __ballot(pend != 0ULL);
                while (ib) {
                    int src = (int)__ffsll(ib) - 1; ib &= ib - 1;
                    u64 kf = rdlane64(pend, src);
                    unsigned j3 = ~(unsigned)kf;
                    if (lane == (int)(j3 & 63u)) {
                        elig |= 1ULL << (j3 >> 6);
                        if (pi0 == 0ULL) pi0 = kf;
                        else if (pi1 == 0ULL) pi1 = kf;
                        else { pend_ovf = true; trip = true; }
                    }
                    pmax = kf > pmax ? kf : pmax;
                    S += s_elog[j3];
                }

                // rare: column 0 with degree > 64 (only item 0 can have it)
                if (b == 0 && da[0] > 64) {
                    for (int base = 64; base < da[0]; base += 64) {
                        u64 p2 = 0ULL;
                        int idx = base + lane;
                        int jj = 0;
                        if (idx < da[0]) {
                            jj = (int)s_edges[e0a[0] + idx];
                            u64 o2 = atomicAdd(&s_key[jj], 0xFFFFFFFF00000000ULL);
                            if ((unsigned)(o2 >> 32) == 1u)
                                p2 = ((o2 & 0xFFFFFFFFULL) << 32) | (unsigned)(~jj);
                        }
                        u64 ib2 = __ballot(p2 != 0ULL);
                        while (ib2) {
                            int src = (int)__ffsll(ib2) - 1; ib2 &= ib2 - 1;
                            u64 kf = rdlane64(p2, src);
                            unsigned j3 = ~(unsigned)kf;
                            if (lane == (int)(j3 & 63u)) {
                                elig |= 1ULL << (j3 >> 6);
                                if (pi0 == 0ULL) pi0 = kf;
                                else if (pi1 == 0ULL) pi1 = kf;
                                else { pend_ovf = true; trip = true; }
                            }
                            pmax = kf > pmax ? kf : pmax;
                            S += s_elog[j3];
                        }
                    }
                }

                if (b + 1 < done) {
                    bool hazard = (pmax > c[b + 1]) || (__ballot(trip) != 0ULL);
                    if (hazard) done = b + 1;
                }
            }
        }

        // ---- rollback unselected items (rare) ----
        if (done < L) {
#pragma unroll
            for (int b = 0; b < 8; ++b) {
                if (b >= done && b < L && lane < da[b])
                    atomicAdd(&s_key[ewa[b]], 0x100000000ULL);
            }
        }

        t += done;

        // ---- compact lists: drop the selcnt selected (front) entries ----
#pragma unroll
        for (int s2 = 0; s2 < 4; ++s2) {
            if (selcnt > s2) { k0 = k1; k1 = k2; k2 = k3; k3 = 0ULL; --valid; }
        }
        // merge pending insertions
        if (pi0) ins4(pi0, k0, k1, k2, k3, valid, ovf);
        if (pi1) ins4(pi1, k0, k1, k2, k3, valid, ovf);
        if (pend_ovf) refill4(s_key, lane, elig, k0, k1, k2, k3, valid, ovf);
    }

    // ---- epilogue: all log_probs in parallel ----
    for (int i = lane; i < NN; i += 64) {
        unsigned si = gssel[i];
        float Si = gslog[i];
        out[si] = -logf((1.0f / s_elog[si]) * Si + 1e-10f);
    }
}

extern "C" void kernel_launch(void* const* d_in, const int* in_sizes, int n_in,
                              void* d_out, int out_size, void* d_ws, size_t ws_size,
                              hipStream_t stream) {
    const float* logits = (const float*)d_in[0];
    const float* adj    = (const float*)d_in[1];
    const float* unif   = (const float*)d_in[2];
    float* out = (float*)d_out;

    char* ws = (char*)d_ws;
    float*          rowsum = (float*)(ws + 0);                    // 12,288
    unsigned*       cnt    = (unsigned*)(ws + 16384);             // 294,912
    unsigned*       colcnt = (unsigned*)(ws + 311296);            // 12,288
    unsigned*       eoff   = (unsigned*)(ws + 323584);            // 12,292
    unsigned*       choff  = (unsigned*)(ws + 339968);            // 294,912
    unsigned short* edges  = (unsigned short*)(ws + 634880);      // 106,496
    float*          elog   = (float*)(ws + 741376);               // 12,288
    unsigned*       keyenc = (unsigned*)(ws + 753664);            // 12,288
    int*            indeg  = (int*)(ws + 765952);                 // 12,288
    float*          gslog  = (float*)(ws + 778240);               // 12,288
    unsigned*       gssel  = (unsigned*)(ws + 790528);            // ends 802,816

    rowsum_kernel<<<NN, 256, 0, stream>>>(adj, rowsum);
    cnt_kernel<<<dim3(NN / 256, NCH), 256, 0, stream>>>(adj, cnt);
    colsum_kernel<<<NN / 256, 256, 0, stream>>>(cnt, colcnt);
    scan_kernel<<<1, 64, 0, stream>>>(colcnt, eoff);
    choff_kernel<<<NN / 256, 256, 0, stream>>>(cnt, eoff, choff);
    fill2_kernel<<<dim3(NN / 256, NCH), 256, 0, stream>>>(adj, choff, edges);
    gumbel_kernel<<<NN / 256, 256, 0, stream>>>(logits, unif, rowsum, out,
                                                elog, keyenc, indeg);
    topo_kernel<<<1, 256, 0, stream>>>(elog, keyenc, indeg, eoff, edges,
                                       gslog, gssel, out);
}

// Round 15
// 1284.796 us; speedup vs baseline: 3.5229x; 3.5229x over previous
//
#include <hip/hip_runtime.h>
#include <math.h>

#define NN 3072
#define EPSG 1e-20f
#define EDGE_CAP 53248          // ~47.2K expected edges + margin
#define RCH 128                 // rows per chunk
#define NCH 24                  // chunks (24*128 = 3072)
typedef unsigned long long u64;

// ---------- prep 1: rowsum0[i] = sum_c adj[i][c] ----------
__global__ __launch_bounds__(256) void rowsum_kernel(const float* __restrict__ adj,
                                                     float* __restrict__ rowsum) {
    int row = blockIdx.x;
    const float* r = adj + (size_t)row * NN;
    float s = 0.f;
    for (int c = threadIdx.x; c < NN; c += 256) s += r[c];
#pragma unroll
    for (int off = 32; off > 0; off >>= 1) s += __shfl_down(s, off);
    __shared__ float ps[4];
    if ((threadIdx.x & 63) == 0) ps[threadIdx.x >> 6] = s;
    __syncthreads();
    if (threadIdx.x == 0) rowsum[row] = (ps[0] + ps[1]) + (ps[2] + ps[3]);
}

// ---------- prep 2a: per-chunk column counts ----------
__global__ __launch_bounds__(256) void cnt_kernel(const float* __restrict__ adj,
                                                  unsigned* __restrict__ cnt) {
    int c = blockIdx.x * 256 + threadIdx.x;
    const float* col = adj + (size_t)(blockIdx.y * RCH) * NN + c;
    unsigned n = 0;
#pragma unroll 4
    for (int i = 0; i < RCH; ++i)
        n += (col[(size_t)i * NN] != 0.0f) ? 1u : 0u;
    cnt[blockIdx.y * NN + c] = n;
}

// ---------- prep 2b: total per-column counts ----------
__global__ __launch_bounds__(256) void colsum_kernel(const unsigned* __restrict__ cnt,
                                                     unsigned* __restrict__ colcnt) {
    int c = blockIdx.x * 256 + threadIdx.x;
    unsigned n = 0;
    for (int by = 0; by < NCH; ++by) n += cnt[by * NN + c];
    colcnt[c] = n;
}

// ---------- prep 2c: exclusive scan of column counts (1 wave) ----------
__global__ __launch_bounds__(64) void scan_kernel(const unsigned* __restrict__ colcnt,
                                                  unsigned* __restrict__ eoff) {
    int lane = threadIdx.x;
    unsigned tot = 0;
    for (int k = 0; k < 48; ++k) tot += colcnt[lane * 48 + k];
    unsigned x = tot;
    for (int off = 1; off < 64; off <<= 1) {
        unsigned y = __shfl_up(x, off);
        if (lane >= off) x += y;
    }
    unsigned run = x - tot;
    for (int k = 0; k < 48; ++k) {
        unsigned c = colcnt[lane * 48 + k];
        eoff[lane * 48 + k] = run;
        run += c;
    }
    if (lane == 63) eoff[NN] = run;
}

// ---------- prep 2d: per-(chunk,column) start offsets ----------
__global__ __launch_bounds__(256) void choff_kernel(const unsigned* __restrict__ cnt,
                                                    const unsigned* __restrict__ eoff,
                                                    unsigned* __restrict__ choff) {
    int c = blockIdx.x * 256 + threadIdx.x;
    unsigned run = eoff[c];
    for (int by = 0; by < NCH; ++by) {
        choff[by * NN + c] = run;
        run += cnt[by * NN + c];
    }
}

// ---------- prep 2e: fill CSC edge lists ----------
__global__ __launch_bounds__(256) void fill2_kernel(const float* __restrict__ adj,
                                                    const unsigned* __restrict__ choff,
                                                    unsigned short* __restrict__ edges) {
    int c = blockIdx.x * 256 + threadIdx.x;
    int r0 = blockIdx.y * RCH;
    unsigned off = choff[blockIdx.y * NN + c];
    const float* col = adj + (size_t)r0 * NN + c;
    for (int i = 0; i < RCH; ++i) {
        if (col[(size_t)i * NN] != 0.0f) {
            if (off < EDGE_CAP) edges[off] = (unsigned short)(r0 + i);
            ++off;
        }
    }
}

// monotonic order-preserving float->u32 map (never 0 for finite inputs)
__device__ __forceinline__ unsigned enc32(float v) {
    unsigned u = __float_as_uint(v);
    return (u & 0x80000000u) ? ~u : (u | 0x80000000u);
}

// ---------- prep 3: gumbel + derived per-node arrays ----------
__global__ __launch_bounds__(256) void gumbel_kernel(const float* __restrict__ logits,
                                                     const float* __restrict__ unif,
                                                     const float* __restrict__ rowsum,
                                                     float* __restrict__ out,
                                                     float* __restrict__ elog,
                                                     unsigned* __restrict__ keyenc,
                                                     unsigned* __restrict__ indeg) {
    int j = blockIdx.x * 256 + threadIdx.x;
    float lg = logits[j];
    float u  = unif[j];
    float g  = lg + (-logf(-logf(u + EPSG) + EPSG));
    out[NN + j] = g;                 // gumbel_logits output
    elog[j] = expf(lg);
    keyenc[j] = enc32(g);
    indeg[j] = (unsigned)(int)rowsum[j];
}

// ---------- prep 4: rank[j] = #{i: key[i]>key[j]} + #{i<j: key[i]==key[j]} ----------
__global__ __launch_bounds__(256) void rank_kernel(const unsigned* __restrict__ keyenc,
                                                   unsigned* __restrict__ rank,
                                                   unsigned* __restrict__ perm) {
    int j = blockIdx.x;
    unsigned kj = keyenc[j];
    unsigned cnt = 0;
    for (int i = threadIdx.x; i < NN; i += 256) {
        unsigned ki = keyenc[i];
        cnt += (ki > kj || (ki == kj && i < j)) ? 1u : 0u;
    }
#pragma unroll
    for (int off = 32; off > 0; off >>= 1) cnt += __shfl_down(cnt, off);
    __shared__ unsigned ps[4];
    if ((threadIdx.x & 63) == 0) ps[threadIdx.x >> 6] = cnt;
    __syncthreads();
    if (threadIdx.x == 0) {
        unsigned r = ps[0] + ps[1] + ps[2] + ps[3];
        rank[j] = r;
        perm[r] = (unsigned)j;
    }
}

// ---------- prep 5: scatter per-node state into rank order ----------
__global__ __launch_bounds__(256) void scatter_kernel(const unsigned* __restrict__ rank,
                                                      const unsigned* __restrict__ eoff,
                                                      const float* __restrict__ elog,
                                                      const unsigned* __restrict__ indeg,
                                                      unsigned* __restrict__ metaR,
                                                      float* __restrict__ elogR,
                                                      unsigned* __restrict__ indegR) {
    int j = blockIdx.x * 256 + threadIdx.x;
    unsigned r = rank[j];
    unsigned e0 = eoff[j];
    unsigned d = eoff[j + 1] - e0;
    metaR[r] = e0 | (d << 20);
    elogR[r] = elog[j];
    indegR[r] = indeg[j];
}

// ---------- prep 6: translate edge targets node->rank ----------
__global__ __launch_bounds__(256) void etrans_kernel(const unsigned short* __restrict__ edges,
                                                     const unsigned* __restrict__ rank,
                                                     unsigned short* __restrict__ edgesR) {
    int i = blockIdx.x * 256 + threadIdx.x;
    if (i < EDGE_CAP + 128) {
        unsigned e = edges[i];
        e = e < NN ? e : NN - 1;          // clamp garbage beyond true total
        edgesR[i] = (unsigned short)rank[e];
    }
}

__device__ __forceinline__ float wsum_f32(float v) {
    int t;
    t = __builtin_amdgcn_update_dpp(0, __float_as_int(v), 0x111, 0xf, 0xf, true); v += __int_as_float(t);
    t = __builtin_amdgcn_update_dpp(0, __float_as_int(v), 0x112, 0xf, 0xf, true); v += __int_as_float(t);
    t = __builtin_amdgcn_update_dpp(0, __float_as_int(v), 0x114, 0xf, 0xf, true); v += __int_as_float(t);
    t = __builtin_amdgcn_update_dpp(0, __float_as_int(v), 0x118, 0xf, 0xf, true); v += __int_as_float(t);
    t = __builtin_amdgcn_update_dpp(0, __float_as_int(v), 0x142, 0xf, 0xf, true); v += __int_as_float(t);
    t = __builtin_amdgcn_update_dpp(0, __float_as_int(v), 0x143, 0xf, 0xf, true); v += __int_as_float(t);
    return v;
}
__device__ __forceinline__ int rdlane(int v, int l) { return __builtin_amdgcn_readlane(v, l); }
__device__ __forceinline__ u64 rdlane64(u64 v, int l) {
    unsigned lo = (unsigned)rdlane((int)(unsigned)v, l);
    unsigned hi = (unsigned)rdlane((int)(unsigned)(v >> 32), l);
    return ((u64)hi << 32) | lo;
}
__device__ __forceinline__ int div48(int j) { return ((j >> 4) * 21846) >> 16; }  // exact for j<3072

// ---------- sequential topo-sort: rank-indexed, bitmask selection ----------
__global__ __launch_bounds__(256) void topo_kernel(const float* __restrict__ elogR,
                                                   const unsigned* __restrict__ indegR,
                                                   const unsigned* __restrict__ metaR,
                                                   const unsigned short* __restrict__ edgesR,
                                                   const unsigned* __restrict__ perm,
                                                   float* __restrict__ gslog,
                                                   unsigned* __restrict__ gssel,
                                                   float* __restrict__ out) {
    __shared__ unsigned       s_indeg[NN];              // keyed by rank
    __shared__ float          s_elog[NN];
    __shared__ unsigned       s_meta[NN];               // eoff | d<<20
    __shared__ unsigned short s_edges[EDGE_CAP + 128];  // rank targets

    const int tid = threadIdx.x;

    // ---- cooperative staging (all 4 waves) ----
    for (int x = tid; x < NN / 4; x += 256) {
        ((uint4*)s_indeg)[x] = ((const uint4*)indegR)[x];
        ((float4*)s_elog)[x] = ((const float4*)elogR)[x];
        ((uint4*)s_meta)[x]  = ((const uint4*)metaR)[x];
    }
    for (int x = tid; x < (EDGE_CAP + 128) / 8; x += 256)
        ((uint4*)s_edges)[x] = ((const uint4*)edgesR)[x];
    __syncthreads();
    if (tid >= 64) return;              // wave 0 continues alone
    const int lane = tid;
    const int base48 = lane * 48;       // lane owns ranks [48l, 48l+48); bit i = rank 48l+i

    // ---- init: eligibility mask + S ----
    u64 mask = 0ULL;
    float S;
    {
        float ssl = 0.f;
        for (int i = 0; i < 48; ++i) {
            int r = base48 + i;
            if (s_indeg[r] == 0u) { mask |= 1ULL << i; ssl += s_elog[r]; }
        }
        float tot = wsum_f32(ssl);
        S = __int_as_float(rdlane(__float_as_int(tot), 63));
    }

    // ---- first selection = lowest eligible rank ----
    int r_cur;
    {
        u64 ball = __ballot(mask != 0ULL);
        int gl = (int)__ffsll(ball) - 1;
        u64 mg = rdlane64(mask, gl);
        r_cur = gl * 48 + (int)__ffsll(mg) - 1;
    }
    {
        int og = div48(r_cur);
        if (lane == og) mask &= ~(1ULL << (r_cur - 48 * og));
    }
    unsigned m0 = s_meta[r_cur];
    unsigned e0_cur = m0 & 0xFFFFFu;
    int d = (int)(m0 >> 20);
    int ew = (int)s_edges[e0_cur + (lane < d ? lane : 0)];
    float elog_cur = s_elog[r_cur];

    // ---- spec = next-lowest eligible rank + prefetch its column ----
    int spec_rank; unsigned e0s; int ds; int ews; float elog_s;
    {
        u64 ball = __ballot(mask != 0ULL);
        u64 bb = ball ? ball : 1ULL;
        int gl = (int)__ffsll(bb) - 1;
        u64 mg = rdlane64(mask, gl);
        u64 mg2 = mg ? mg : 1ULL;
        spec_rank = ball ? (gl * 48 + (int)__ffsll(mg2) - 1) : 0x7FFFFFFF;
        int sc = spec_rank < NN ? spec_rank : 0;
        unsigned ms = s_meta[sc];
        e0s = ms & 0xFFFFFu; ds = (int)(ms >> 20);
        ews = (int)s_edges[e0s + (lane < ds ? lane : 0)];
        elog_s = s_elog[sc];
    }

    for (int t = 0; t < NN; ++t) {
        // record (S = pre-removal sum, includes r_cur)
        if (lane == 0) { gslog[t] = S; gssel[t] = (unsigned)r_cur; }

        // ---- atomic decrement of this column's targets (edges pre-loaded) ----
        bool act = lane < d;
        unsigned old = 0xFFFFFFFFu;
        if (act) old = atomicSub(&s_indeg[ew], 1u);
        int pend = (act && old == 1u) ? ew : -1;

        S -= elog_cur;

        // ---- merge insertions: set mask bits + min inserted rank + S ----
        int min_ins = 0x7FFFFFFF;
        u64 ib = __ballot(pend >= 0);
        while (ib) {
            int src = (int)__ffsll(ib) - 1; ib &= ib - 1;
            int rr = rdlane(pend, src);
            int og = div48(rr);
            if (lane == og) mask |= 1ULL << (rr - 48 * og);
            min_ins = rr < min_ins ? rr : min_ins;
            S += s_elog[rr];
        }

        // rare slow path: degree > 64
        if (d > 64) {
            for (int base = 64; base < d; base += 64) {
                int idx = base + lane;
                int p2 = -1;
                if (idx < d) {
                    int rr2 = (int)s_edges[e0_cur + idx];
                    unsigned o2 = atomicSub(&s_indeg[rr2], 1u);
                    if (o2 == 1u) p2 = rr2;
                }
                u64 ib2 = __ballot(p2 >= 0);
                while (ib2) {
                    int src = (int)__ffsll(ib2) - 1; ib2 &= ib2 - 1;
                    int rr = rdlane(p2, src);
                    int og = div48(rr);
                    if (lane == og) mask |= 1ULL << (rr - 48 * og);
                    min_ins = rr < min_ins ? rr : min_ins;
                    S += s_elog[rr];
                }
            }
        }

        // ---- next = min(spec, best insertion) ----
        int next = spec_rank < min_ins ? spec_rank : min_ins;

        float elog_next; int dn; int ewn; unsigned e0n;
        if (next != spec_rank) {
            // spec miss (rare, uniform): serial reload
            int nc = next < NN ? next : 0;
            unsigned m = s_meta[nc];
            e0n = m & 0xFFFFFu; dn = (int)(m >> 20);
            ewn = (int)s_edges[e0n + (lane < dn ? lane : 0)];
            elog_next = s_elog[nc];
        } else { e0n = e0s; dn = ds; ewn = ews; elog_next = elog_s; }

        // clear next's bit
        if (next < NN) {
            int og = div48(next);
            if (lane == og) mask &= ~(1ULL << (next - 48 * og));
        }

        // ---- spec2 = new lowest eligible + prefetch (covered by next iter) ----
        {
            u64 ball = __ballot(mask != 0ULL);
            u64 bb = ball ? ball : 1ULL;
            int gl = (int)__ffsll(bb) - 1;
            u64 mg = rdlane64(mask, gl);
            u64 mg2 = mg ? mg : 1ULL;
            spec_rank = ball ? (gl * 48 + (int)__ffsll(mg2) - 1) : 0x7FFFFFFF;
            int sc = spec_rank < NN ? spec_rank : 0;
            unsigned ms = s_meta[sc];
            e0s = ms & 0xFFFFFu; ds = (int)(ms >> 20);
            ews = (int)s_edges[e0s + (lane < ds ? lane : 0)];
            elog_s = s_elog[sc];
        }

        r_cur = next; d = dn; ew = ewn; e0_cur = e0n; elog_cur = elog_next;
    }

    // ---- epilogue: all log_probs in parallel (rank -> node via perm) ----
    for (int i = lane; i < NN; i += 64) {
        unsigned rr = gssel[i];
        float Si = gslog[i];
        int node = (int)perm[rr];
        out[node] = -logf((1.0f / s_elog[rr]) * Si + 1e-10f);
    }
}

extern "C" void kernel_launch(void* const* d_in, const int* in_sizes, int n_in,
                              void* d_out, int out_size, void* d_ws, size_t ws_size,
                              hipStream_t stream) {
    const float* logits = (const float*)d_in[0];
    const float* adj    = (const float*)d_in[1];
    const float* unif   = (const float*)d_in[2];
    float* out = (float*)d_out;

    char* ws = (char*)d_ws;
    float*          rowsum = (float*)(ws + 0);
    unsigned*       cnt    = (unsigned*)(ws + 16384);
    unsigned*       colcnt = (unsigned*)(ws + 311296);
    unsigned*       eoff   = (unsigned*)(ws + 323584);
    unsigned*       choff  = (unsigned*)(ws + 339968);
    unsigned short* edges  = (unsigned short*)(ws + 634880);   // EDGE_CAP u16
    float*          elog   = (float*)(ws + 741376);
    unsigned*       keyenc = (unsigned*)(ws + 753664);
    unsigned*       indeg  = (unsigned*)(ws + 765952);
    unsigned*       rank   = (unsigned*)(ws + 778240);
    unsigned*       perm   = (unsigned*)(ws + 790528);
    unsigned*       metaR  = (unsigned*)(ws + 802816);
    float*          elogR  = (float*)(ws + 815104);
    unsigned*       indegR = (unsigned*)(ws + 827392);
    unsigned short* edgesR = (unsigned short*)(ws + 839680);   // EDGE_CAP+128 u16
    float*          gslog  = (float*)(ws + 946432);
    unsigned*       gssel  = (unsigned*)(ws + 958720);         // ends 971,008

    rowsum_kernel<<<NN, 256, 0, stream>>>(adj, rowsum);
    cnt_kernel<<<dim3(NN / 256, NCH), 256, 0, stream>>>(adj, cnt);
    colsum_kernel<<<NN / 256, 256, 0, stream>>>(cnt, colcnt);
    scan_kernel<<<1, 64, 0, stream>>>(colcnt, eoff);
    choff_kernel<<<NN / 256, 256, 0, stream>>>(cnt, eoff, choff);
    fill2_kernel<<<dim3(NN / 256, NCH), 256, 0, stream>>>(adj, choff, edges);
    gumbel_kernel<<<NN / 256, 256, 0, stream>>>(logits, unif, rowsum, out,
                                                elog, keyenc, indeg);
    rank_kernel<<<NN, 256, 0, stream>>>(keyenc, rank, perm);
    scatter_kernel<<<NN / 256, 256, 0, stream>>>(rank, eoff, elog, indeg,
                                                 metaR, elogR, indegR);
    etrans_kernel<<<(EDGE_CAP + 128 + 255) / 256, 256, 0, stream>>>(edges, rank, edgesR);
    topo_kernel<<<1, 256, 0, stream>>>(elogR, indegR, metaR, edgesR, perm,
                                       gslog, gssel, out);
}